// Round 2
// baseline (815.546 us; speedup 1.0000x reference)
//
#include <hip/hip_runtime.h>
#include <math.h>

#define A_ 4
#define M_ 32
#define S_ 48000
#define L_ 16000
#define NB_ 8
#define BIN_ 64
#define TWO_PI_F 6.28318530717958647692f
#define INV_SR (1.0f / 48000.0f)
#define CHUNK 1024
#define NCHUNK 47   /* ceil(48000/1024) */

/* workspace layout (bytes) */
#define INC_OFF   0u                      /* float2[A_*M_*S_]  = 49,152,000 B */
#define SIG_OFF   49152000u               /* float[A_*S_]      =    768,000 B */
#define PART_OFF  49920000u               /* double2[128*47]   =     96,256 B */
#define CONST_OFF 50016256u               /* F[8] flin[32] alpha[32] beta[32] amp[128] */
#define WS_NEEDED (CONST_OFF + 232u * 4u)

__device__ __forceinline__ float softplusf(float x) {
    return fmaxf(x, 0.f) + log1pf(expf(-fabsf(x)));
}

/* ---------- tiny precompute: F/ALPHA/BETA tables, per-mode f_lin/alpha/beta, amp ---------- */
__global__ void k_precompute(const float* __restrict__ flin_p,
                             const float* __restrict__ alpha_p,
                             const float* __restrict__ beta_p,
                             const float* __restrict__ amp_v,
                             float* __restrict__ cst) {
    __shared__ float sF[NB_], sA[BIN_], sB[BIN_];
    int tid = threadIdx.x;
    if (tid < NB_) {
        double lf = log(20.0) + (double)tid * ((log(8000.0) - log(20.0)) / 7.0);
        float v = (float)exp(lf);
        sF[tid] = v;
        cst[tid] = v;
    }
    if (tid < BIN_) {
        double la = log(0.3) + (double)tid * ((log(300.0) - log(0.3)) / 63.0);
        sA[tid] = (float)exp(la);
        double lb = log(1e-10) + (double)tid * ((log(1e-7) - log(1e-10)) / 63.0);
        sB[tid] = (float)exp(lb);
    }
    __syncthreads();
    if (tid < M_) {
        float sum = 0.f, dot = 0.f;
        for (int i = 0; i < NB_; ++i) {
            float sp = softplusf(flin_p[tid * NB_ + i]);
            sum += sp; dot = fmaf(sp, sF[i], dot);
        }
        cst[8 + tid] = dot / sum;

        sum = 0.f; dot = 0.f;
        for (int i = 0; i < BIN_; ++i) {
            float sp = softplusf(alpha_p[tid * BIN_ + i]);
            sum += sp; dot = fmaf(sp, sA[i], dot);
        }
        cst[40 + tid] = dot / sum;

        sum = 0.f; dot = 0.f;
        for (int i = 0; i < BIN_; ++i) {
            float sp = softplusf(beta_p[tid * BIN_ + i]);
            sum += sp; dot = fmaf(sp, sB[i], dot);
        }
        cst[72 + tid] = dot / sum;
    }
    if (tid < A_ * M_) {
        float x = amp_v[tid];
        float sg = 1.f / (1.f + expf(-x));
        cst[104 + tid] = 2.f * powf(sg, 2.30258509299404568402f) + 1e-7f;
    }
}

/* ---------- phase1: increments + per-chunk sums ---------- */
__global__ __launch_bounds__(256) void k_phase1(const float* __restrict__ nl,
                                                const float* __restrict__ cst,
                                                float2* __restrict__ inc,
                                                double2* __restrict__ part) {
    int row = blockIdx.y;          /* a*M+m */
    int m = row & 31;
    int chunk = blockIdx.x;
    int tid = threadIdx.x;

    float Fv[8];
#pragma unroll
    for (int i = 0; i < 8; ++i) Fv[i] = cst[i];
    float flin = cst[8 + m];
    float al   = cst[40 + m];
    float be   = cst[72 + m];

    const float4* nl4 = (const float4*)nl;
    int s0 = chunk * CHUNK + tid * 4;
    double dsum = 0.0, fsum = 0.0;

#pragma unroll
    for (int k = 0; k < 4; ++k) {
        int s = s0 + k;
        if (s < S_) {
            size_t off = ((size_t)row * S_ + s) * 2;   /* float4 units */
            float4 x0 = nl4[off];
            float4 x1 = nl4[off + 1];
            float xs[8] = {x0.x, x0.y, x0.z, x0.w, x1.x, x1.y, x1.z, x1.w};
            float sum = 0.f, dot = 0.f;
#pragma unroll
            for (int i = 0; i < 8; ++i) {
                float sp = softplusf(xs[i]);
                sum += sp;
                dot = fmaf(sp, Fv[i], dot);
            }
            float und = flin + 0.3f * (dot / sum);
            float w = TWO_PI_F * und;
            float lbd = w * w;
            float damp = 0.5f * fmaf(be, lbd, al);
            float freq = sqrtf(lbd - damp * damp) * (1.0f / TWO_PI_F);
            float2 v;
            v.x = damp * INV_SR;
            v.y = freq * INV_SR;
            inc[(size_t)row * S_ + s] = v;
            dsum += (double)v.x;
            fsum += (double)v.y;
        }
    }

    __shared__ double rd[256], rf[256];
    rd[tid] = dsum; rf[tid] = fsum;
    __syncthreads();
    for (int o = 128; o > 0; o >>= 1) {
        if (tid < o) { rd[tid] += rd[tid + o]; rf[tid] += rf[tid + o]; }
        __syncthreads();
    }
    if (tid == 0) {
        double2 p; p.x = rd[0]; p.y = rf[0];
        part[row * NCHUNK + chunk] = p;
    }
}

/* ---------- phase2: per-row exclusive scan of chunk sums (f64) ---------- */
__global__ void k_phase2(double2* __restrict__ part) {
    int r = threadIdx.x;
    if (r < A_ * M_) {
        double cx = 0.0, cy = 0.0;
        for (int c = 0; c < NCHUNK; ++c) {
            double2 t = part[r * NCHUNK + c];
            double2 e; e.x = cx; e.y = cy;
            part[r * NCHUNK + c] = e;
            cx += t.x; cy += t.y;
        }
    }
}

/* ---------- phase3: block scan + signal accumulation ---------- */
__global__ __launch_bounds__(256) void k_phase3(const float2* __restrict__ inc,
                                                const double2* __restrict__ part,
                                                const float* __restrict__ cst,
                                                float* __restrict__ sig) {
    int row = blockIdx.y;
    int chunk = blockIdx.x;
    int tid = threadIdx.x;
    int a = row >> 5;

    double2 carry = part[row * NCHUNK + chunk];
    float amp = cst[104 + row];

    int s0 = chunk * CHUNK + tid * 4;
    float2 v[4];
#pragma unroll
    for (int k = 0; k < 4; ++k) {
        int s = s0 + k;
        if (s < S_) v[k] = inc[(size_t)row * S_ + s];
        else { v[k].x = 0.f; v[k].y = 0.f; }
    }
    float lpx[4], lpy[4];
    float rx = 0.f, ry = 0.f;
#pragma unroll
    for (int k = 0; k < 4; ++k) {
        rx += v[k].x; lpx[k] = rx;
        ry += v[k].y; lpy[k] = ry;
    }

    __shared__ double sx[256], sy[256];
    sx[tid] = (double)rx; sy[tid] = (double)ry;
    __syncthreads();
    for (int o = 1; o < 256; o <<= 1) {
        double ax = (tid >= o) ? sx[tid - o] : 0.0;
        double ay = (tid >= o) ? sy[tid - o] : 0.0;
        __syncthreads();
        sx[tid] += ax; sy[tid] += ay;
        __syncthreads();
    }
    double ex = ((tid > 0) ? sx[tid - 1] : 0.0) + carry.x;
    double ey = ((tid > 0) ? sy[tid - 1] : 0.0) + carry.y;

#pragma unroll
    for (int k = 0; k < 4; ++k) {
        int s = s0 + k;
        if (s < S_) {
            double cd = ex + (double)lpx[k];
            if (cd < 16.0) {
                double cf = ey + (double)lpy[k];
                float ph = (float)(cf - floor(cf));
                float val = amp * expf(-(float)cd) * sinf(TWO_PI_F * ph);
                atomicAdd(&sig[a * S_ + s], val);
            }
        }
    }
}

/* ---------- conv: depthwise FIR, LDS-tiled, 8x8 register blocking ---------- */
#define CT 2048    /* outputs per block */
#define CJ 512     /* taps per LDS chunk */
#define CG 2048    /* taps per j-group (8 groups cover 16000 padded to 16384) */
#define TTILES 24  /* ceil(48000/2048) */

__global__ __launch_bounds__(256) void k_conv(const float* __restrict__ sig,
                                              const float* __restrict__ forces,
                                              float* __restrict__ out) {
    __shared__ float fs[CJ];
    __shared__ float ss[CT + CJ];   /* 2560 */
    int tid = threadIdx.x;
    int t0 = blockIdx.x * CT;
    int a  = blockIdx.y;
    int jg = blockIdx.z * CG;

    const float* sa = sig + (size_t)a * S_;
    const float* fa = forces + (size_t)a * L_;

    float acc[8];
#pragma unroll
    for (int r = 0; r < 8; ++r) acc[r] = 0.f;

    for (int c = 0; c < 4; ++c) {
        int j0 = jg + c * CJ;
        __syncthreads();   /* previous inner-loop reads done before overwrite */
#pragma unroll
        for (int k = 0; k < CJ / 256; ++k) {
            int i = tid + k * 256;
            int j = j0 + i;
            fs[i] = (j < L_) ? fa[j] : 0.f;
        }
        int base_s = t0 - j0 - (CJ - 1);
        int nz = 0;
#pragma unroll
        for (int k = 0; k < (CT + CJ) / 256; ++k) {
            int i = tid + k * 256;
            int s = base_s + i;
            float vv = (s >= 0 && s < S_) ? sa[s] : 0.f;
            ss[i] = vv;
            nz |= (vv != 0.f);
        }
        if (__syncthreads_or(nz)) {
#pragma unroll 2
            for (int jj = 0; jj < CJ; jj += 8) {
                const float4* f4 = (const float4*)(fs + jj);
                float4 fq0 = f4[0], fq1 = f4[1];
                float fr[8] = {fq0.x, fq0.y, fq0.z, fq0.w, fq1.x, fq1.y, fq1.z, fq1.w};
                int b = tid * 8 + (CJ - 8) - jj;
                const float4* s4 = (const float4*)(ss + b);
                float4 w0 = s4[0], w1 = s4[1], w2 = s4[2], w3 = s4[3];
                float w[16] = {w0.x, w0.y, w0.z, w0.w, w1.x, w1.y, w1.z, w1.w,
                               w2.x, w2.y, w2.z, w2.w, w3.x, w3.y, w3.z, w3.w};
#pragma unroll
                for (int q = 0; q < 8; ++q)
#pragma unroll
                    for (int r = 0; r < 8; ++r)
                        acc[r] = fmaf(fr[q], w[7 + r - q], acc[r]);
            }
        }
    }

#pragma unroll
    for (int r = 0; r < 8; ++r) {
        int t = t0 + tid * 8 + r;
        if (t < S_) atomicAdd(&out[(size_t)a * S_ + t], acc[r]);
    }
}

extern "C" void kernel_launch(void* const* d_in, const int* in_sizes, int n_in,
                              void* d_out, int out_size, void* d_ws, size_t ws_size,
                              hipStream_t stream) {
    if (ws_size < (size_t)WS_NEEDED) return;  /* cannot proceed safely */

    const float* flin_p  = (const float*)d_in[0];
    const float* nl_p    = (const float*)d_in[1];
    const float* alpha_p = (const float*)d_in[2];
    const float* beta_p  = (const float*)d_in[3];
    const float* amp_v   = (const float*)d_in[4];
    const float* forces  = (const float*)d_in[5];
    float* out = (float*)d_out;

    char* ws = (char*)d_ws;
    float2*  inc  = (float2*)(ws + INC_OFF);
    float*   sig  = (float*)(ws + SIG_OFF);
    double2* part = (double2*)(ws + PART_OFF);
    float*   cst  = (float*)(ws + CONST_OFF);

    hipMemsetAsync(sig, 0, (size_t)A_ * S_ * sizeof(float), stream);
    hipMemsetAsync(out, 0, (size_t)out_size * sizeof(float), stream);

    hipLaunchKernelGGL(k_precompute, dim3(1), dim3(256), 0, stream,
                       flin_p, alpha_p, beta_p, amp_v, cst);
    hipLaunchKernelGGL(k_phase1, dim3(NCHUNK, A_ * M_), dim3(256), 0, stream,
                       nl_p, cst, inc, part);
    hipLaunchKernelGGL(k_phase2, dim3(1), dim3(128), 0, stream, part);
    hipLaunchKernelGGL(k_phase3, dim3(NCHUNK, A_ * M_), dim3(256), 0, stream,
                       inc, part, cst, sig);
    hipLaunchKernelGGL(k_conv, dim3(TTILES, A_, 8), dim3(256), 0, stream,
                       sig, forces, out);
}

// Round 3
// 551.150 us; speedup vs baseline: 1.4797x; 1.4797x over previous
//
#include <hip/hip_runtime.h>
#include <math.h>

#define A_ 4
#define M_ 32
#define S_ 48000
#define L_ 16000
#define NB_ 8
#define BIN_ 64
#define TWO_PI_F 6.28318530717958647692f
#define INV_SR (1.0f / 48000.0f)
#define CHUNK 1024
#define NCHUNK 47   /* ceil(48000/1024) */

/* workspace layout (bytes) */
#define INC_OFF   0u                      /* float2[A_*M_*S_]  = 49,152,000 B */
#define SIG_OFF   49152000u               /* float[A_*S_]      =    768,000 B */
#define PART_OFF  49920000u               /* double2[128*47]   =     96,256 B */
#define CONST_OFF 50016256u               /* F[8] flin[32] alpha[32] beta[32] amp[128] */
#define WS_NEEDED (CONST_OFF + 232u * 4u)

__device__ __forceinline__ float softplusf(float x) {
    /* max(x,0) + log1p(exp(-|x|)); 1+t in (1,2] so plain log is exact enough */
    float t = __expf(-fabsf(x));
    return fmaxf(x, 0.f) + __logf(1.f + t);
}

/* ---------- tiny precompute ---------- */
__global__ void k_precompute(const float* __restrict__ flin_p,
                             const float* __restrict__ alpha_p,
                             const float* __restrict__ beta_p,
                             const float* __restrict__ amp_v,
                             float* __restrict__ cst) {
    __shared__ float sF[NB_], sA[BIN_], sB[BIN_];
    int tid = threadIdx.x;
    if (tid < NB_) {
        double lf = log(20.0) + (double)tid * ((log(8000.0) - log(20.0)) / 7.0);
        float v = (float)exp(lf);
        sF[tid] = v;
        cst[tid] = v;
    }
    if (tid < BIN_) {
        double la = log(0.3) + (double)tid * ((log(300.0) - log(0.3)) / 63.0);
        sA[tid] = (float)exp(la);
        double lb = log(1e-10) + (double)tid * ((log(1e-7) - log(1e-10)) / 63.0);
        sB[tid] = (float)exp(lb);
    }
    __syncthreads();
    if (tid < M_) {
        float sum = 0.f, dot = 0.f;
        for (int i = 0; i < NB_; ++i) {
            float sp = softplusf(flin_p[tid * NB_ + i]);
            sum += sp; dot = fmaf(sp, sF[i], dot);
        }
        cst[8 + tid] = dot / sum;

        sum = 0.f; dot = 0.f;
        for (int i = 0; i < BIN_; ++i) {
            float sp = softplusf(alpha_p[tid * BIN_ + i]);
            sum += sp; dot = fmaf(sp, sA[i], dot);
        }
        cst[40 + tid] = dot / sum;

        sum = 0.f; dot = 0.f;
        for (int i = 0; i < BIN_; ++i) {
            float sp = softplusf(beta_p[tid * BIN_ + i]);
            sum += sp; dot = fmaf(sp, sB[i], dot);
        }
        cst[72 + tid] = dot / sum;
    }
    if (tid < A_ * M_) {
        float x = amp_v[tid];
        float sg = 1.f / (1.f + __expf(-x));
        float lg = __logf(sg);
        cst[104 + tid] = 2.f * __expf(2.30258509299404568402f * lg) + 1e-7f;
    }
}

/* ---------- phase1: increments + per-chunk sums ---------- */
__global__ __launch_bounds__(256) void k_phase1(const float* __restrict__ nl,
                                                const float* __restrict__ cst,
                                                float2* __restrict__ inc,
                                                double2* __restrict__ part) {
    int row = blockIdx.y;          /* a*M+m */
    int m = row & 31;
    int chunk = blockIdx.x;
    int tid = threadIdx.x;

    float Fv[8];
#pragma unroll
    for (int i = 0; i < 8; ++i) Fv[i] = cst[i];
    float flin = cst[8 + m];
    float al   = cst[40 + m];
    float be   = cst[72 + m];

    const float4* nl4 = (const float4*)nl;
    int s0 = chunk * CHUNK + tid * 4;
    double dsum = 0.0, fsum = 0.0;

#pragma unroll
    for (int k = 0; k < 4; ++k) {
        int s = s0 + k;
        if (s < S_) {
            size_t off = ((size_t)row * S_ + s) * 2;   /* float4 units */
            float4 x0 = nl4[off];
            float4 x1 = nl4[off + 1];
            float xs[8] = {x0.x, x0.y, x0.z, x0.w, x1.x, x1.y, x1.z, x1.w};
            float sum = 0.f, dot = 0.f;
#pragma unroll
            for (int i = 0; i < 8; ++i) {
                float sp = softplusf(xs[i]);
                sum += sp;
                dot = fmaf(sp, Fv[i], dot);
            }
            float und = flin + 0.3f * (dot / sum);
            float w = TWO_PI_F * und;
            float lbd = w * w;
            float damp = 0.5f * fmaf(be, lbd, al);
            float freq = sqrtf(lbd - damp * damp) * (1.0f / TWO_PI_F);
            float2 v;
            v.x = damp * INV_SR;
            v.y = freq * INV_SR;
            inc[(size_t)row * S_ + s] = v;
            dsum += (double)v.x;
            fsum += (double)v.y;
        }
    }

    __shared__ double rd[256], rf[256];
    rd[tid] = dsum; rf[tid] = fsum;
    __syncthreads();
    for (int o = 128; o > 0; o >>= 1) {
        if (tid < o) { rd[tid] += rd[tid + o]; rf[tid] += rf[tid + o]; }
        __syncthreads();
    }
    if (tid == 0) {
        double2 p; p.x = rd[0]; p.y = rf[0];
        part[row * NCHUNK + chunk] = p;
    }
}

/* ---------- phase2: per-row exclusive scan of chunk sums (f64) ---------- */
__global__ void k_phase2(double2* __restrict__ part) {
    int r = threadIdx.x;
    if (r < A_ * M_) {
        double cx = 0.0, cy = 0.0;
        for (int c = 0; c < NCHUNK; ++c) {
            double2 t = part[r * NCHUNK + c];
            double2 e; e.x = cx; e.y = cy;
            part[r * NCHUNK + c] = e;
            cx += t.x; cy += t.y;
        }
    }
}

/* ---------- phase3: block scan + signal accumulation ---------- */
__global__ __launch_bounds__(256) void k_phase3(const float2* __restrict__ inc,
                                                const double2* __restrict__ part,
                                                const float* __restrict__ cst,
                                                float* __restrict__ sig) {
    int row = blockIdx.y;
    int chunk = blockIdx.x;
    int tid = threadIdx.x;
    int a = row >> 5;

    double2 carry = part[row * NCHUNK + chunk];
    float amp = cst[104 + row];

    int s0 = chunk * CHUNK + tid * 4;
    float2 v[4];
#pragma unroll
    for (int k = 0; k < 4; ++k) {
        int s = s0 + k;
        if (s < S_) v[k] = inc[(size_t)row * S_ + s];
        else { v[k].x = 0.f; v[k].y = 0.f; }
    }
    float lpx[4], lpy[4];
    float rx = 0.f, ry = 0.f;
#pragma unroll
    for (int k = 0; k < 4; ++k) {
        rx += v[k].x; lpx[k] = rx;
        ry += v[k].y; lpy[k] = ry;
    }

    __shared__ double sx[256], sy[256];
    sx[tid] = (double)rx; sy[tid] = (double)ry;
    __syncthreads();
    for (int o = 1; o < 256; o <<= 1) {
        double ax = (tid >= o) ? sx[tid - o] : 0.0;
        double ay = (tid >= o) ? sy[tid - o] : 0.0;
        __syncthreads();
        sx[tid] += ax; sy[tid] += ay;
        __syncthreads();
    }
    double ex = ((tid > 0) ? sx[tid - 1] : 0.0) + carry.x;
    double ey = ((tid > 0) ? sy[tid - 1] : 0.0) + carry.y;

#pragma unroll
    for (int k = 0; k < 4; ++k) {
        int s = s0 + k;
        if (s < S_) {
            double cd = ex + (double)lpx[k];
            if (cd < 16.0) {
                double cf = ey + (double)lpy[k];
                float ph = (float)(cf - floor(cf));
                float val = amp * __expf(-(float)cd) * __sinf(TWO_PI_F * ph);
                atomicAdd(&sig[a * S_ + s], val);
            }
        }
    }
}

/* ---------- conv: depthwise FIR, padded LDS + register sliding window ---------- */
#define CT 2048    /* outputs per block */
#define CJ 512     /* taps per LDS chunk */
#define CG 2048    /* taps per j-group (8 groups cover 16000 padded to 16384) */
#define TTILES 24  /* ceil(48000/2048) */
#define PADI(i) ((i) + (((i) >> 5) << 2))         /* float-index pad: +4 per 32 */
#define PADG(g) ((g) + ((g) >> 3))                /* float4-group pad */
#define SSPAD 2880                                /* PADI(2559)=2875 -> 2880 */

__device__ __forceinline__ void load8(const float* __restrict__ ss, int fbase,
                                      float* __restrict__ dst) {
    int g = fbase >> 2;
    float4 a = ((const float4*)ss)[PADG(g)];
    float4 b = ((const float4*)ss)[PADG(g + 1)];
    dst[0] = a.x; dst[1] = a.y; dst[2] = a.z; dst[3] = a.w;
    dst[4] = b.x; dst[5] = b.y; dst[6] = b.z; dst[7] = b.w;
}

__device__ __forceinline__ void fma8x8(const float* __restrict__ fs, int jj,
                                       const float* __restrict__ lo,
                                       const float* __restrict__ hi,
                                       float* __restrict__ acc) {
    const float4* f4 = (const float4*)(fs + jj);
    float4 fq0 = f4[0], fq1 = f4[1];
    float fr[8] = {fq0.x, fq0.y, fq0.z, fq0.w, fq1.x, fq1.y, fq1.z, fq1.w};
#pragma unroll
    for (int q = 0; q < 8; ++q) {
#pragma unroll
        for (int r = 0; r < 8; ++r) {
            int x = r + 7 - q;                    /* 0..14, compile-time */
            float w = (x < 8) ? lo[x] : hi[x - 8];
            acc[r] = fmaf(fr[q], w, acc[r]);
        }
    }
}

__global__ __launch_bounds__(256) void k_conv(const float* __restrict__ sig,
                                              const float* __restrict__ forces,
                                              float* __restrict__ out) {
    __shared__ float fs[CJ];
    __shared__ float ss[SSPAD];
    int tid = threadIdx.x;
    int t0 = blockIdx.x * CT;
    int a  = blockIdx.y;
    int jg = blockIdx.z * CG;

    const float* sa = sig + (size_t)a * S_;
    const float* fa = forces + (size_t)a * L_;

    float acc[8];
#pragma unroll
    for (int r = 0; r < 8; ++r) acc[r] = 0.f;

    for (int c = 0; c < 4; ++c) {
        int j0 = jg + c * CJ;
        __syncthreads();   /* previous inner-loop reads done before overwrite */
#pragma unroll
        for (int k = 0; k < CJ / 256; ++k) {
            int i = tid + k * 256;
            int j = j0 + i;
            fs[i] = (j < L_) ? fa[j] : 0.f;
        }
        int base_s = t0 - j0 - (CJ - 1);
        int nz = 0;
#pragma unroll
        for (int k = 0; k < 10; ++k) {            /* 2560 floats staged, padded */
            int i = tid + k * 256;
            int s = base_s + i;
            float vv = (s >= 0 && s < S_) ? sa[s] : 0.f;
            ss[PADI(i)] = vv;
            nz |= (vv != 0.f);
        }
        if (__syncthreads_or(nz)) {
            /* window [b, b+15] = (lo|hi); slides down 8 floats per 8-tap step */
            float wa[8], wb[8];
            int b = 8 * tid + 504;                /* b for jj = 0 */
            load8(ss, b, wa);                     /* lo */
            load8(ss, b + 8, wb);                 /* hi */
#pragma unroll 4
            for (int p = 0; p < 32; ++p) {
                int jj = p * 16;
                fma8x8(fs, jj, wa, wb, acc);      /* window (wa, wb) */
                load8(ss, b - 8, wb);             /* new lo -> wb (old hi dead) */
                fma8x8(fs, jj + 8, wb, wa, acc);  /* window (wb, wa) */
                if (p < 31) load8(ss, b - 16, wa);
                b -= 16;
            }
        }
    }

#pragma unroll
    for (int r = 0; r < 8; ++r) {
        int t = t0 + tid * 8 + r;
        if (t < S_) atomicAdd(&out[(size_t)a * S_ + t], acc[r]);
    }
}

extern "C" void kernel_launch(void* const* d_in, const int* in_sizes, int n_in,
                              void* d_out, int out_size, void* d_ws, size_t ws_size,
                              hipStream_t stream) {
    if (ws_size < (size_t)WS_NEEDED) return;  /* cannot proceed safely */

    const float* flin_p  = (const float*)d_in[0];
    const float* nl_p    = (const float*)d_in[1];
    const float* alpha_p = (const float*)d_in[2];
    const float* beta_p  = (const float*)d_in[3];
    const float* amp_v   = (const float*)d_in[4];
    const float* forces  = (const float*)d_in[5];
    float* out = (float*)d_out;

    char* ws = (char*)d_ws;
    float2*  inc  = (float2*)(ws + INC_OFF);
    float*   sig  = (float*)(ws + SIG_OFF);
    double2* part = (double2*)(ws + PART_OFF);
    float*   cst  = (float*)(ws + CONST_OFF);

    hipMemsetAsync(sig, 0, (size_t)A_ * S_ * sizeof(float), stream);
    hipMemsetAsync(out, 0, (size_t)out_size * sizeof(float), stream);

    hipLaunchKernelGGL(k_precompute, dim3(1), dim3(256), 0, stream,
                       flin_p, alpha_p, beta_p, amp_v, cst);
    hipLaunchKernelGGL(k_phase1, dim3(NCHUNK, A_ * M_), dim3(256), 0, stream,
                       nl_p, cst, inc, part);
    hipLaunchKernelGGL(k_phase2, dim3(1), dim3(128), 0, stream, part);
    hipLaunchKernelGGL(k_phase3, dim3(NCHUNK, A_ * M_), dim3(256), 0, stream,
                       inc, part, cst, sig);
    hipLaunchKernelGGL(k_conv, dim3(TTILES, A_, 8), dim3(256), 0, stream,
                       sig, forces, out);
}

// Round 7
// 446.778 us; speedup vs baseline: 1.8254x; 1.2336x over previous
//
#include <hip/hip_runtime.h>
#include <hip/hip_bf16.h>
#include <math.h>

#define A_ 4
#define M_ 32
#define S_ 48000
#define L_ 16000
#define NB_ 8
#define BIN_ 64
#define TWO_PI_F 6.28318530717958647692f
#define INV_SR (1.0f / 48000.0f)
#define NCHUNK 47            /* ceil(48000/1024) */
#define NROW 128             /* A_*M_ */
#define SBPAD 16000          /* zeros before signal in sigbf */
#define SBLEN 64256          /* 16000 + 48000 + 256 tail pad */
#define SB_PLANE 257024      /* shorts per plane: 4*SBLEN */
#define NKT 501              /* K blocks of 32 taps: w reaches 1000 (incl.) */
#define FB_PLANE 1026048u    /* shorts per plane: 4*501*64*8 */
#define UT_PER_A 188         /* ceil(48128/256) */

/* ---- workspace layout (bytes) ---- */
#define CST_OFF    0u                /* 232 floats (pad to 1024) */
#define SIG_OFF    1024u             /* float[4*48000] = 768000 */
#define PART_OFF   769024u           /* double2[128*47] = 96256 */
#define SIGBF_OFF  865280u           /* ushort[2][4*64256] = 1028096 */
#define FRAGB_OFF  1893376u          /* ushort[2][1026048] = 4104192 */
#define WS_NEEDED  5997568u

typedef __attribute__((ext_vector_type(8))) short bf16x8;
typedef __attribute__((ext_vector_type(4))) float f32x4;

__device__ __forceinline__ float softplusf(float x) {
    float t = __expf(-fabsf(x));
    return fmaxf(x, 0.f) + __logf(1.f + t);
}
__device__ __forceinline__ unsigned short bfbits(float v) {
    __hip_bfloat16 h = __float2bfloat16(v);
    return *(unsigned short*)&h;
}
__device__ __forceinline__ float bf2f(unsigned short u) {
    unsigned x = ((unsigned)u) << 16;
    return *(float*)&x;
}

/* ---------- tiny precompute ---------- */
__global__ void k_precompute(const float* __restrict__ flin_p,
                             const float* __restrict__ alpha_p,
                             const float* __restrict__ beta_p,
                             const float* __restrict__ amp_v,
                             float* __restrict__ cst) {
    __shared__ float sF[NB_], sA[BIN_], sB[BIN_];
    int tid = threadIdx.x;
    if (tid < NB_) {
        double lf = log(20.0) + (double)tid * ((log(8000.0) - log(20.0)) / 7.0);
        float v = (float)exp(lf);
        sF[tid] = v; cst[tid] = v;
    }
    if (tid < BIN_) {
        double la = log(0.3) + (double)tid * ((log(300.0) - log(0.3)) / 63.0);
        sA[tid] = (float)exp(la);
        double lb = log(1e-10) + (double)tid * ((log(1e-7) - log(1e-10)) / 63.0);
        sB[tid] = (float)exp(lb);
    }
    __syncthreads();
    if (tid < M_) {
        float sum = 0.f, dot = 0.f;
        for (int i = 0; i < NB_; ++i) {
            float sp = softplusf(flin_p[tid * NB_ + i]);
            sum += sp; dot = fmaf(sp, sF[i], dot);
        }
        cst[8 + tid] = dot / sum;
        sum = 0.f; dot = 0.f;
        for (int i = 0; i < BIN_; ++i) {
            float sp = softplusf(alpha_p[tid * BIN_ + i]);
            sum += sp; dot = fmaf(sp, sA[i], dot);
        }
        cst[40 + tid] = dot / sum;
        sum = 0.f; dot = 0.f;
        for (int i = 0; i < BIN_; ++i) {
            float sp = softplusf(beta_p[tid * BIN_ + i]);
            sum += sp; dot = fmaf(sp, sB[i], dot);
        }
        cst[72 + tid] = dot / sum;
    }
    if (tid < A_ * M_) {
        float x = amp_v[tid];
        float sg = 1.f / (1.f + __expf(-x));
        cst[104 + tid] = 2.f * __expf(2.30258509299404568402f * __logf(sg)) + 1e-7f;
    }
}

/* ---------- forces Toeplitz fragments, split bf16 hi/lo planes ---------- */
__global__ __launch_bounds__(256) void k_fragB(const float* __restrict__ forces,
                                               unsigned short* __restrict__ fragB) {
    int t = blockIdx.x * 256 + threadIdx.x;      /* (a, kk, lane): 4*501*64 */
    if (t >= A_ * NKT * 64) return;
    int l  = t & 63;
    int kk = (t >> 6) % NKT;
    int a  = t / (NKT * 64);
    int v  = l & 15, hq = l >> 4;
    unsigned short hi[8], lo[8];
#pragma unroll
    for (int j = 0; j < 8; ++j) {
        int k = hq * 8 + j;
        int r = k & 15, hw = k >> 4;
        int fj = 32 * kk + 16 * hw + v - r;      /* B[k][v] = f[16w + v - r] */
        float fv = (fj >= 0 && fj < L_) ? forces[a * L_ + fj] : 0.f;
        hi[j] = bfbits(fv);
        lo[j] = bfbits(fv - bf2f(hi[j]));
    }
    uint4 ph, pl;
    ph.x = (unsigned)hi[0] | ((unsigned)hi[1] << 16);
    ph.y = (unsigned)hi[2] | ((unsigned)hi[3] << 16);
    ph.z = (unsigned)hi[4] | ((unsigned)hi[5] << 16);
    ph.w = (unsigned)hi[6] | ((unsigned)hi[7] << 16);
    pl.x = (unsigned)lo[0] | ((unsigned)lo[1] << 16);
    pl.y = (unsigned)lo[2] | ((unsigned)lo[3] << 16);
    pl.z = (unsigned)lo[4] | ((unsigned)lo[5] << 16);
    pl.w = (unsigned)lo[6] | ((unsigned)lo[7] << 16);
    ((uint4*)fragB)[t] = ph;
    ((uint4*)fragB)[FB_PLANE / 8 + t] = pl;
}

/* ---------- shared increment computation ---------- */
__device__ __forceinline__ void inc_partials(const float4* __restrict__ nl4,
                                             const float* __restrict__ cst,
                                             int row, int s0,
                                             float* lpx, float* lpy,
                                             float& rx, float& ry) {
    int m = row & 31;
    float Fv[8];
#pragma unroll
    for (int i = 0; i < 8; ++i) Fv[i] = cst[i];
    float flin = cst[8 + m], al = cst[40 + m], be = cst[72 + m];
    rx = 0.f; ry = 0.f;
#pragma unroll
    for (int k = 0; k < 4; ++k) {
        int s = s0 + k;
        float vx = 0.f, vy = 0.f;
        if (s < S_) {
            size_t off = ((size_t)row * S_ + s) * 2;
            float4 x0 = nl4[off];
            float4 x1 = nl4[off + 1];
            float xs[8] = {x0.x, x0.y, x0.z, x0.w, x1.x, x1.y, x1.z, x1.w};
            float sum = 0.f, dot = 0.f;
#pragma unroll
            for (int i = 0; i < 8; ++i) {
                float sp = softplusf(xs[i]);
                sum += sp; dot = fmaf(sp, Fv[i], dot);
            }
            float und = flin + 0.3f * (dot / sum);
            float w = TWO_PI_F * und;
            float lbd = w * w;
            float damp = 0.5f * fmaf(be, lbd, al);
            float freq = sqrtf(lbd - damp * damp) * (1.0f / TWO_PI_F);
            vx = damp * INV_SR;
            vy = freq * INV_SR;
        }
        rx += vx; lpx[k] = rx;
        ry += vy; lpy[k] = ry;
    }
}

/* ---------- pass 1: per-chunk sums ---------- */
__global__ __launch_bounds__(256) void k_sum(const float* __restrict__ nl,
                                             const float* __restrict__ cst,
                                             double2* __restrict__ part) {
    int chunk = blockIdx.x, row = blockIdx.y, tid = threadIdx.x;
    float lpx[4], lpy[4], rx, ry;
    inc_partials((const float4*)nl, cst, row, chunk * 1024 + tid * 4, lpx, lpy, rx, ry);

    __shared__ double rd[256], rf[256];
    rd[tid] = (double)rx; rf[tid] = (double)ry;
    __syncthreads();
    for (int o = 128; o > 0; o >>= 1) {
        if (tid < o) { rd[tid] += rd[tid + o]; rf[tid] += rf[tid + o]; }
        __syncthreads();
    }
    if (tid == 0) {
        double2 p; p.x = rd[0]; p.y = rf[0];
        part[row * NCHUNK + chunk] = p;
    }
}

/* ---------- pass 2: per-row serial exclusive scan (f64) ---------- */
__global__ void k_phase2(double2* __restrict__ part) {
    int r = threadIdx.x;
    if (r < NROW) {
        double cx = 0.0, cy = 0.0;
        for (int c = 0; c < NCHUNK; ++c) {
            double2 t = part[r * NCHUNK + c];
            double2 e; e.x = cx; e.y = cy;
            part[r * NCHUNK + c] = e;
            cx += t.x; cy += t.y;
        }
    }
}

/* ---------- pass 3: recompute increments, block scan + carry, eval ---------- */
__global__ __launch_bounds__(256) void k_eval(const float* __restrict__ nl,
                                              const float* __restrict__ cst,
                                              const double2* __restrict__ part,
                                              float* __restrict__ sig) {
    int chunk = blockIdx.x, row = blockIdx.y, tid = threadIdx.x;
    int a = row >> 5;
    int s0 = chunk * 1024 + tid * 4;
    float lpx[4], lpy[4], rx, ry;
    inc_partials((const float4*)nl, cst, row, s0, lpx, lpy, rx, ry);

    double2 carry = part[row * NCHUNK + chunk];
    float amp = cst[104 + row];

    __shared__ double sx[256], sy[256];
    sx[tid] = (double)rx; sy[tid] = (double)ry;
    __syncthreads();
    for (int o = 1; o < 256; o <<= 1) {
        double ax = (tid >= o) ? sx[tid - o] : 0.0;
        double ay = (tid >= o) ? sy[tid - o] : 0.0;
        __syncthreads();
        sx[tid] += ax; sy[tid] += ay;
        __syncthreads();
    }
    double ex = ((tid > 0) ? sx[tid - 1] : 0.0) + carry.x;
    double ey = ((tid > 0) ? sy[tid - 1] : 0.0) + carry.y;

#pragma unroll
    for (int k = 0; k < 4; ++k) {
        int s = s0 + k;
        if (s < S_) {
            double cd = ex + (double)lpx[k];
            if (cd < 16.0) {
                double cf = ey + (double)lpy[k];
                float ph = (float)(cf - floor(cf));
                float val = amp * __expf(-(float)cd) * __sinf(TWO_PI_F * ph);
                atomicAdd(&sig[a * S_ + s], val);
            }
        }
    }
}

/* ---------- sig f32 -> padded bf16 hi/lo planes ---------- */
__global__ __launch_bounds__(256) void k_convert(const float* __restrict__ sig,
                                                 unsigned short* __restrict__ sigbf) {
    int i = blockIdx.x * 256 + threadIdx.x;      /* 4*64256 = 257024 */
    if (i >= A_ * SBLEN) return;
    int a = i / SBLEN, p = i - a * SBLEN;
    int s = p - SBPAD;
    float v = (s >= 0 && s < S_) ? sig[a * S_ + s] : 0.f;
    unsigned short hi = bfbits(v);
    sigbf[i] = hi;
    sigbf[SB_PLANE + i] = bfbits(v - bf2f(hi));
}

/* ---------- conv as block-Toeplitz MFMA GEMM, 3-term split bf16 ---------- */
__global__ __launch_bounds__(512) void k_conv(const unsigned short* __restrict__ sigbf,
                                              const unsigned short* __restrict__ fragB,
                                              float* __restrict__ out) {
    int tile = blockIdx.x;                       /* 0..751 */
    int a = tile / UT_PER_A, ut = tile - a * UT_PER_A;
    int u0 = ut * 16;
    int tid = threadIdx.x;
    int wv = tid >> 6;
    int l  = tid & 63;
    int du = l & 15, hq = l >> 4, hw = hq >> 1, hr = hq & 1;

    int nkk = (u0 >> 1) + 9;                     /* covers all contributing kk */
    if (nkk > NKT) nkk = NKT;

    const unsigned short* sH = sigbf + (size_t)a * SBLEN;
    const unsigned short* sL = sH + SB_PLANE;
    int ebase = SBPAD + 16 * (u0 + du) - 16 * hw + 8 * hr;
    const unsigned short* fH = fragB + (((size_t)a * NKT) * 64 + l) * 8;
    const unsigned short* fL = fH + FB_PLANE;

    f32x4 acc0 = {0.f, 0.f, 0.f, 0.f};
    f32x4 acc1 = {0.f, 0.f, 0.f, 0.f};

    for (int kk = wv; kk < nkk; kk += 16) {
        {
            int e = ebase - 32 * kk;
            bf16x8 ah = *(const bf16x8*)(sH + e);
            bf16x8 al = *(const bf16x8*)(sL + e);
            bf16x8 bh = *(const bf16x8*)(fH + (size_t)kk * 512);
            bf16x8 bl = *(const bf16x8*)(fL + (size_t)kk * 512);
            acc0 = __builtin_amdgcn_mfma_f32_16x16x32_bf16(ah, bh, acc0, 0, 0, 0);
            acc0 = __builtin_amdgcn_mfma_f32_16x16x32_bf16(al, bh, acc0, 0, 0, 0);
            acc0 = __builtin_amdgcn_mfma_f32_16x16x32_bf16(ah, bl, acc0, 0, 0, 0);
        }
        int k2 = kk + 8;
        if (k2 < nkk) {
            int e = ebase - 32 * k2;
            bf16x8 ah = *(const bf16x8*)(sH + e);
            bf16x8 al = *(const bf16x8*)(sL + e);
            bf16x8 bh = *(const bf16x8*)(fH + (size_t)k2 * 512);
            bf16x8 bl = *(const bf16x8*)(fL + (size_t)k2 * 512);
            acc1 = __builtin_amdgcn_mfma_f32_16x16x32_bf16(ah, bh, acc1, 0, 0, 0);
            acc1 = __builtin_amdgcn_mfma_f32_16x16x32_bf16(al, bh, acc1, 0, 0, 0);
            acc1 = __builtin_amdgcn_mfma_f32_16x16x32_bf16(ah, bl, acc1, 0, 0, 0);
        }
    }
    acc0 = acc0 + acc1;

    __shared__ float red[8][256];
#pragma unroll
    for (int r = 0; r < 4; ++r)                   /* C: row=(l>>4)*4+r, col=l&15 */
        red[wv][(hq * 4 + r) * 16 + (l & 15)] = acc0[r];
    __syncthreads();

    if (tid < 256) {
        float s = 0.f;
#pragma unroll
        for (int w2 = 0; w2 < 8; ++w2) s += red[w2][tid];
        int t = u0 * 16 + tid;
        if (t < S_) out[(size_t)a * S_ + t] = s;
    }
}

extern "C" void kernel_launch(void* const* d_in, const int* in_sizes, int n_in,
                              void* d_out, int out_size, void* d_ws, size_t ws_size,
                              hipStream_t stream) {
    if (ws_size < (size_t)WS_NEEDED) return;

    const float* flin_p  = (const float*)d_in[0];
    const float* nl_p    = (const float*)d_in[1];
    const float* alpha_p = (const float*)d_in[2];
    const float* beta_p  = (const float*)d_in[3];
    const float* amp_v   = (const float*)d_in[4];
    const float* forces  = (const float*)d_in[5];
    float* out = (float*)d_out;

    char* ws = (char*)d_ws;
    float*          cst    = (float*)(ws + CST_OFF);
    float*          sig    = (float*)(ws + SIG_OFF);
    double2*        part   = (double2*)(ws + PART_OFF);
    unsigned short* sigbf  = (unsigned short*)(ws + SIGBF_OFF);
    unsigned short* fragB  = (unsigned short*)(ws + FRAGB_OFF);

    hipMemsetAsync(sig, 0, (size_t)A_ * S_ * sizeof(float), stream);

    hipLaunchKernelGGL(k_precompute, dim3(1), dim3(256), 0, stream,
                       flin_p, alpha_p, beta_p, amp_v, cst);
    hipLaunchKernelGGL(k_fragB, dim3(501), dim3(256), 0, stream, forces, fragB);
    hipLaunchKernelGGL(k_sum, dim3(NCHUNK, NROW), dim3(256), 0, stream,
                       nl_p, cst, part);
    hipLaunchKernelGGL(k_phase2, dim3(1), dim3(128), 0, stream, part);
    hipLaunchKernelGGL(k_eval, dim3(NCHUNK, NROW), dim3(256), 0, stream,
                       nl_p, cst, part, sig);
    hipLaunchKernelGGL(k_convert, dim3(1004), dim3(256), 0, stream, sig, sigbf);
    hipLaunchKernelGGL(k_conv, dim3(A_ * UT_PER_A), dim3(512), 0, stream,
                       sigbf, fragB, out);
}